// Round 1
// baseline (1400.426 us; speedup 1.0000x reference)
//
#include <hip/hip_runtime.h>
#include <hip/hip_bf16.h>

// LSTM: T=2048, B=512, INPUT=42, HIDDEN=64. Output uses ONLY batch element 511
// (reference indexes lstm_out[:, -1, :]). So we compute the recurrence for a
// single batch row: 2048 sequential steps of a 256x64 matvec + activations.

#define T_STEPS 2048
#define BATCH   512
#define NIN     42
#define NH      64
#define NG      256   // 4*NH

// ---------------- Kernel 1: input projection for batch row 511 ----------------
// xp[t][g] = dot(x[t,511,:], W_ih[g,:]) + b_ih[g] + b_hh[g]
__global__ __launch_bounds__(256) void xproj_kernel(
    const float* __restrict__ x, const float* __restrict__ W_ih,
    const float* __restrict__ b_ih, const float* __restrict__ b_hh,
    float* __restrict__ xp)
{
    const int t = blockIdx.x;
    const int g = threadIdx.x;           // 0..255
    __shared__ float xs[NIN];
    const float* xrow = x + ((size_t)t * BATCH + (BATCH - 1)) * NIN;
    if (threadIdx.x < NIN) xs[threadIdx.x] = xrow[threadIdx.x];
    __syncthreads();
    const float* wr = W_ih + g * NIN;
    float s = b_ih[g] + b_hh[g];
#pragma unroll
    for (int i = 0; i < NIN; ++i) s += wr[i] * xs[i];
    xp[t * NG + g] = s;
}

// ---------------- Kernel 2: sequential LSTM scan (1 block, 256 threads) -------
// Lane layout: lane = u*4 + kc  (u = hidden unit 0..63, kc = k-chunk 0..3).
// Each lane: partial sums of gates {i,f,g,o} of unit u over k in [16kc,16kc+16).
// Butterfly shfl_xor(1),(2) completes all 4 gate sums in every lane.
__global__ __launch_bounds__(256) void lstm_scan_kernel(
    const float* __restrict__ W_hh, const float* __restrict__ xp,
    float* __restrict__ hout)
{
    const int lane = threadIdx.x;       // 0..255
    const int kc   = lane & 3;          // k-chunk
    const int u    = lane >> 2;         // hidden unit

    __shared__ __align__(16) float hbuf[2][NH];
    if (lane < NH) { hbuf[0][lane] = 0.f; hbuf[1][lane] = 0.f; }

    // Per-lane weights: w{g}[k] = W_hh[g*64+u][kc*16+k]
    float w0[16], w1[16], w2[16], w3[16];
#pragma unroll
    for (int k4 = 0; k4 < 4; ++k4) {
        float4 v;
        v = ((const float4*)(W_hh + (0 * NH + u) * NH + kc * 16))[k4];
        w0[k4*4+0]=v.x; w0[k4*4+1]=v.y; w0[k4*4+2]=v.z; w0[k4*4+3]=v.w;
        v = ((const float4*)(W_hh + (1 * NH + u) * NH + kc * 16))[k4];
        w1[k4*4+0]=v.x; w1[k4*4+1]=v.y; w1[k4*4+2]=v.z; w1[k4*4+3]=v.w;
        v = ((const float4*)(W_hh + (2 * NH + u) * NH + kc * 16))[k4];
        w2[k4*4+0]=v.x; w2[k4*4+1]=v.y; w2[k4*4+2]=v.z; w2[k4*4+3]=v.w;
        v = ((const float4*)(W_hh + (3 * NH + u) * NH + kc * 16))[k4];
        w3[k4*4+0]=v.x; w3[k4*4+1]=v.y; w3[k4*4+2]=v.z; w3[k4*4+3]=v.w;
    }

    float c = 0.f;
    // prefetch xp for t=0 (kc==0 lanes carry the bias/xp contribution)
    float xp0 = 0.f, xp1 = 0.f, xp2 = 0.f, xp3 = 0.f;
    if (kc == 0) {
        const float* xr = xp;  // t=0
        xp0 = xr[0 * NH + u]; xp1 = xr[1 * NH + u];
        xp2 = xr[2 * NH + u]; xp3 = xr[3 * NH + u];
    }
    __syncthreads();

    int p = 0;
    for (int t = 0; t < T_STEPS; ++t) {
        // load h chunk [16kc, 16kc+16)
        const float4* hb = (const float4*)hbuf[p];
        float4 hv0 = hb[kc * 4 + 0];
        float4 hv1 = hb[kc * 4 + 1];
        float4 hv2 = hb[kc * 4 + 2];
        float4 hv3 = hb[kc * 4 + 3];
        float hk[16] = { hv0.x, hv0.y, hv0.z, hv0.w,
                         hv1.x, hv1.y, hv1.z, hv1.w,
                         hv2.x, hv2.y, hv2.z, hv2.w,
                         hv3.x, hv3.y, hv3.z, hv3.w };

        float s0 = xp0, s1 = xp1, s2 = xp2, s3 = xp3;  // 0 in kc!=0 lanes

        // prefetch next step's xp (hidden under the FMA block)
        if (kc == 0 && t + 1 < T_STEPS) {
            const float* xr = xp + (size_t)(t + 1) * NG;
            xp0 = xr[0 * NH + u]; xp1 = xr[1 * NH + u];
            xp2 = xr[2 * NH + u]; xp3 = xr[3 * NH + u];
        }

#pragma unroll
        for (int k = 0; k < 16; ++k) {
            s0 += w0[k] * hk[k];
            s1 += w1[k] * hk[k];
            s2 += w2[k] * hk[k];
            s3 += w3[k] * hk[k];
        }

        // butterfly over the 4 k-chunks (lanes u*4 .. u*4+3)
        s0 += __shfl_xor(s0, 1); s1 += __shfl_xor(s1, 1);
        s2 += __shfl_xor(s2, 1); s3 += __shfl_xor(s3, 1);
        s0 += __shfl_xor(s0, 2); s1 += __shfl_xor(s1, 2);
        s2 += __shfl_xor(s2, 2); s3 += __shfl_xor(s3, 2);

        // activations: gates order i, f, g, o
        float i_ = 1.f / (1.f + __expf(-s0));
        float f_ = 1.f / (1.f + __expf(-s1));
        float g_ = 1.f - 2.f / (1.f + __expf(2.f * s2));   // tanh
        float o_ = 1.f / (1.f + __expf(-s3));

        c = f_ * c + i_ * g_;
        float th = 1.f - 2.f / (1.f + __expf(2.f * c));    // tanh(c)
        float hn = o_ * th;

        if (kc == 0) {
            hbuf[1 - p][u] = hn;          // double buffer: one barrier/step
            hout[(size_t)t * NH + u] = hn;
        }
        __syncthreads();
        p ^= 1;
    }
}

// ---------------- Kernel 3: output projection out[t] = W_out @ h_t + b_out ----
__global__ __launch_bounds__(256) void outproj_kernel(
    const float* __restrict__ hout, const float* __restrict__ W_out,
    const float* __restrict__ b_out, float* __restrict__ out)
{
    int idx = blockIdx.x * blockDim.x + threadIdx.x;   // T*2
    if (idx >= T_STEPS * 2) return;
    int t = idx >> 1, o = idx & 1;
    const float* hr = hout + (size_t)t * NH;
    const float* wr = W_out + o * NH;
    float s = b_out[o];
#pragma unroll
    for (int j = 0; j < NH; ++j) s += hr[j] * wr[j];
    out[t * 2 + o] = s;
}

extern "C" void kernel_launch(void* const* d_in, const int* in_sizes, int n_in,
                              void* d_out, int out_size, void* d_ws, size_t ws_size,
                              hipStream_t stream) {
    const float* x     = (const float*)d_in[0];
    const float* W_ih  = (const float*)d_in[1];
    const float* W_hh  = (const float*)d_in[2];
    const float* b_ih  = (const float*)d_in[3];
    const float* b_hh  = (const float*)d_in[4];
    const float* W_out = (const float*)d_in[5];
    const float* b_out = (const float*)d_in[6];
    float* out = (float*)d_out;

    // workspace layout: xp (T*256 floats) | hout (T*64 floats)  = 2.5 MB
    float* xp   = (float*)d_ws;
    float* hout = xp + (size_t)T_STEPS * NG;

    xproj_kernel<<<T_STEPS, 256, 0, stream>>>(x, W_ih, b_ih, b_hh, xp);
    lstm_scan_kernel<<<1, 256, 0, stream>>>(W_hh, xp, hout);
    outproj_kernel<<<(T_STEPS * 2 + 255) / 256, 256, 0, stream>>>(hout, W_out, b_out, out);
}